// Round 3
// baseline (982.108 us; speedup 1.0000x reference)
//
#include <hip/hip_runtime.h>

typedef __bf16 bf16_t;
typedef __bf16 bf16x8 __attribute__((ext_vector_type(8)));
typedef float floatx4 __attribute__((ext_vector_type(4)));

#define MFMA16(a, b, c) __builtin_amdgcn_mfma_f32_16x16x32_bf16((a), (b), (c), 0, 0, 0)

__global__ void detect_kernel(const unsigned short* __restrict__ q, int* flag)
{
    __shared__ int cnt;
    if (threadIdx.x == 0) cnt = 0;
    __syncthreads();
    int local = 0;
    for (int i = threadIdx.x; i < 65536; i += 256) {
        unsigned short u = q[i];
        if ((u & 0x7F80u) == 0x7F80u) local++;
    }
    atomicAdd(&cnt, local);
    __syncthreads();
    if (threadIdx.x == 0) flag[0] = (cnt >= 8) ? 1 : 0;
}

__device__ inline void cvt16_f32(const float* __restrict__ p, bf16x8& lo, bf16x8& hi)
{
    float4 a = ((const float4*)p)[0];
    float4 b = ((const float4*)p)[1];
    float4 c = ((const float4*)p)[2];
    float4 d = ((const float4*)p)[3];
    lo[0] = (bf16_t)a.x; lo[1] = (bf16_t)a.y; lo[2] = (bf16_t)a.z; lo[3] = (bf16_t)a.w;
    lo[4] = (bf16_t)b.x; lo[5] = (bf16_t)b.y; lo[6] = (bf16_t)b.z; lo[7] = (bf16_t)b.w;
    hi[0] = (bf16_t)c.x; hi[1] = (bf16_t)c.y; hi[2] = (bf16_t)c.z; hi[3] = (bf16_t)c.w;
    hi[4] = (bf16_t)d.x; hi[5] = (bf16_t)d.y; hi[6] = (bf16_t)d.z; hi[7] = (bf16_t)d.w;
}

// GEMM: Y[row,n] = (sum_k X[row,k]*W[n,k] + bias[n]) * scale
// W/bias external (dtype per flag). X external iff xext=1 (then offset by
// xelemoff elements in its native dtype), else internal bf16.
// mode 0: Y row-major external dtype; mode 1: Y internal bf16 scattered to
// [B,H,Tdim,64].
__global__ __launch_bounds__(256) void gemm_bt_kernel(
    const void* __restrict__ Xv, const void* __restrict__ Wv,
    const void* __restrict__ biasv, void* __restrict__ Yv,
    const int* __restrict__ flag,
    int K, int N, float scale, int mode, int Brows, int Tdim, int xext,
    size_t xelemoff)
{
    __shared__ __attribute__((aligned(16))) bf16_t As[128 * 40];
    __shared__ __attribute__((aligned(16))) bf16_t Bs[128 * 40];

    const int f32 = flag[0];
    const int xf32 = xext ? f32 : 0;

    const int tid = threadIdx.x;
    const int wv = tid >> 6, lane = tid & 63;
    const int qd = lane >> 4, l16 = lane & 15;
    const int wm = (wv >> 1) * 64, wn = (wv & 1) * 64;
    const int rm0 = blockIdx.x * 128, cn0 = blockIdx.y * 128;

    const int srow = tid >> 1;
    const int sseg = (tid & 1) * 16;
    const size_t xoff = xelemoff + (size_t)(rm0 + srow) * K + sseg;
    const size_t woff = (size_t)(cn0 + srow) * K + sseg;
    const bf16_t* Xh = (const bf16_t*)Xv + xoff;
    const float*  Xf = (const float*)Xv + xoff;
    const bf16_t* Wh = (const bf16_t*)Wv + woff;
    const float*  Wf = (const float*)Wv + woff;
    bf16_t* Asw = &As[srow * 40 + sseg];
    bf16_t* Bsw = &Bs[srow * 40 + sseg];

    floatx4 acc[4][4];
#pragma unroll
    for (int i = 0; i < 4; i++)
#pragma unroll
        for (int j = 0; j < 4; j++) acc[i][j] = (floatx4){0.f, 0.f, 0.f, 0.f};

    for (int k0 = 0; k0 < K; k0 += 32) {
        bf16x8 x0, x1, w0, w1;
        if (xf32) {
            cvt16_f32(Xf + k0, x0, x1);
        } else {
            x0 = *(const bf16x8*)(Xh + k0);
            x1 = *(const bf16x8*)(Xh + k0 + 8);
        }
        if (f32) {
            cvt16_f32(Wf + k0, w0, w1);
        } else {
            w0 = *(const bf16x8*)(Wh + k0);
            w1 = *(const bf16x8*)(Wh + k0 + 8);
        }
        __syncthreads();
        *(bf16x8*)(Asw) = x0;
        *(bf16x8*)(Asw + 8) = x1;
        *(bf16x8*)(Bsw) = w0;
        *(bf16x8*)(Bsw + 8) = w1;
        __syncthreads();

        bf16x8 af[4], bfg[4];
#pragma unroll
        for (int mi = 0; mi < 4; mi++)
            af[mi] = *(const bf16x8*)(&As[(wm + mi * 16 + l16) * 40 + qd * 8]);
#pragma unroll
        for (int ni = 0; ni < 4; ni++)
            bfg[ni] = *(const bf16x8*)(&Bs[(wn + ni * 16 + l16) * 40 + qd * 8]);
#pragma unroll
        for (int mi = 0; mi < 4; mi++)
#pragma unroll
            for (int ni = 0; ni < 4; ni++)
                acc[mi][ni] = MFMA16(af[mi], bfg[ni], acc[mi][ni]);
    }

#pragma unroll
    for (int ni = 0; ni < 4; ni++) {
        const int col = cn0 + wn + ni * 16 + l16;
        const float bv = f32 ? ((const float*)biasv)[col]
                             : (float)((const bf16_t*)biasv)[col];
#pragma unroll
        for (int mi = 0; mi < 4; mi++) {
            const int row0 = rm0 + wm + mi * 16 + qd * 4;
#pragma unroll
            for (int r = 0; r < 4; r++) {
                const int row = row0 + r;
                const float val = (acc[mi][ni][r] + bv) * scale;
                if (mode == 0) {
                    if (f32) ((float*)Yv)[(size_t)row * N + col] = val;
                    else ((bf16_t*)Yv)[(size_t)row * N + col] = (bf16_t)val;
                } else {
                    const int t = row / Brows, b = row % Brows;
                    const int h = col >> 6, d = col & 63;
                    ((bf16_t*)Yv)[(((size_t)(b * 16 + h) * Tdim) + t) * 64 + d] = (bf16_t)val;
                }
            }
        }
    }
}

__global__ __launch_bounds__(256) void attn_kernel(
    const bf16_t* __restrict__ Qg, const bf16_t* __restrict__ Kg,
    const bf16_t* __restrict__ Vg, const bf16_t* __restrict__ KMg,
    const bf16_t* __restrict__ VMg, const void* __restrict__ posv,
    const void* __restrict__ mbiasv, bf16_t* __restrict__ att,
    const int* __restrict__ flag, int T, int Mlen)
{
    __shared__ __attribute__((aligned(16))) bf16_t Qs[64 * 72];
    __shared__ __attribute__((aligned(16))) bf16_t Ks[64 * 72];
    __shared__ __attribute__((aligned(16))) bf16_t Vts[64 * 72];
    __shared__ __attribute__((aligned(16))) bf16_t Ps[4][16 * 72];

    const int f32 = flag[0];
    const int tid = threadIdx.x;
    const int wv = tid >> 6, lane = tid & 63;
    const int qd = lane >> 4, l16 = lane & 15;
    const int qt = blockIdx.x;
    const int bh = blockIdx.y;
    const int h = bh & 15;
    const int t0 = qt * 64;

    const bf16_t* Qb = Qg + (size_t)bh * T * 64;
    const bf16_t* Kb = Kg + (size_t)bh * T * 64;
    const bf16_t* Vb = Vg + (size_t)bh * T * 64;
    const bf16_t* KMb = KMg + (size_t)bh * Mlen * 64;
    const bf16_t* VMb = VMg + (size_t)bh * Mlen * 64;
    const float*  posf = (const float*)posv + (size_t)h * T * T;
    const bf16_t* posh = (const bf16_t*)posv + (size_t)h * T * T;

    const int srow = tid >> 2;
    const int sseg = (tid & 3) * 16;

    {
        bf16x8 v0 = *(const bf16x8*)(Qb + (size_t)(t0 + srow) * 64 + sseg);
        bf16x8 v1 = *(const bf16x8*)(Qb + (size_t)(t0 + srow) * 64 + sseg + 8);
        *(bf16x8*)(&Qs[srow * 72 + sseg]) = v0;
        *(bf16x8*)(&Qs[srow * 72 + sseg + 8]) = v1;
    }
    __syncthreads();
    const bf16x8 a0 = *(const bf16x8*)(&Qs[(wv * 16 + l16) * 72 + qd * 8]);
    const bf16x8 a1 = *(const bf16x8*)(&Qs[(wv * 16 + l16) * 72 + 32 + qd * 8]);

    floatx4 Ol[4], Om[4];
    float ml[4], ll[4], mm2[4], lm[4];
#pragma unroll
    for (int i = 0; i < 4; i++) {
        Ol[i] = (floatx4){0.f, 0.f, 0.f, 0.f};
        Om[i] = (floatx4){0.f, 0.f, 0.f, 0.f};
        ml[i] = -1e9f; ll[i] = 0.f; mm2[i] = -1e9f; lm[i] = 0.f;
    }

    const int trow_base = t0 + wv * 16 + qd * 4;
    bf16_t* Pw = &Ps[wv][0];

    for (int st = 0; st <= qt; ++st) {
        const int s0 = st * 64;
        __syncthreads();
        {
            const bf16_t* Kp = Kb + (size_t)(s0 + srow) * 64 + sseg;
            bf16x8 kv0 = *(const bf16x8*)(Kp);
            bf16x8 kv1 = *(const bf16x8*)(Kp + 8);
            *(bf16x8*)(&Ks[srow * 72 + sseg]) = kv0;
            *(bf16x8*)(&Ks[srow * 72 + sseg + 8]) = kv1;
            const bf16_t* Vp = Vb + (size_t)(s0 + srow) * 64 + sseg;
            bf16x8 vv0 = *(const bf16x8*)(Vp);
            bf16x8 vv1 = *(const bf16x8*)(Vp + 8);
#pragma unroll
            for (int j = 0; j < 8; j++) Vts[(sseg + j) * 72 + srow] = vv0[j];
#pragma unroll
            for (int j = 0; j < 8; j++) Vts[(sseg + 8 + j) * 72 + srow] = vv1[j];
        }
        __syncthreads();

        float sv[4][4];
        const bool diag = (st == qt);
#pragma unroll
        for (int ni = 0; ni < 4; ni++) {
            floatx4 c = (floatx4){0.f, 0.f, 0.f, 0.f};
            bf16x8 b0 = *(const bf16x8*)(&Ks[(ni * 16 + l16) * 72 + qd * 8]);
            bf16x8 b1 = *(const bf16x8*)(&Ks[(ni * 16 + l16) * 72 + 32 + qd * 8]);
            c = MFMA16(a0, b0, c);
            c = MFMA16(a1, b1, c);
            const int sg = s0 + ni * 16 + l16;
#pragma unroll
            for (int r = 0; r < 4; r++) {
                const int tg = trow_base + r;
                const size_t pidx = (size_t)tg * T + sg;
                const float pe = f32 ? posf[pidx] : (float)posh[pidx];
                float val = c[r] + pe;
                if (diag && sg > tg) val = -1e9f;
                sv[ni][r] = val;
            }
        }

#pragma unroll
        for (int r = 0; r < 4; r++) {
            float mt = fmaxf(fmaxf(sv[0][r], sv[1][r]), fmaxf(sv[2][r], sv[3][r]));
            mt = fmaxf(mt, __shfl_xor(mt, 1));
            mt = fmaxf(mt, __shfl_xor(mt, 2));
            mt = fmaxf(mt, __shfl_xor(mt, 4));
            mt = fmaxf(mt, __shfl_xor(mt, 8));
            const float mnew = fmaxf(ml[r], mt);
            const float alpha = __expf(ml[r] - mnew);
            ml[r] = mnew;
            float ls = 0.f;
#pragma unroll
            for (int ni = 0; ni < 4; ni++) {
                const float p = __expf(sv[ni][r] - mnew);
                sv[ni][r] = p;
                ls += p;
            }
            ls += __shfl_xor(ls, 1);
            ls += __shfl_xor(ls, 2);
            ls += __shfl_xor(ls, 4);
            ls += __shfl_xor(ls, 8);
            ll[r] = ll[r] * alpha + ls;
#pragma unroll
            for (int ni = 0; ni < 4; ni++) Ol[ni][r] *= alpha;
#pragma unroll
            for (int ni = 0; ni < 4; ni++)
                Pw[(qd * 4 + r) * 72 + ni * 16 + l16] = (bf16_t)sv[ni][r];
        }
        __syncthreads();
#pragma unroll
        for (int ks = 0; ks < 2; ks++) {
            bf16x8 pf = *(const bf16x8*)(&Pw[l16 * 72 + ks * 32 + qd * 8]);
#pragma unroll
            for (int ni = 0; ni < 4; ni++) {
                bf16x8 vf = *(const bf16x8*)(&Vts[(ni * 16 + l16) * 72 + ks * 32 + qd * 8]);
                Ol[ni] = MFMA16(pf, vf, Ol[ni]);
            }
        }
    }

    for (int st = 0; st < Mlen / 64; ++st) {
        const int s0 = st * 64;
        __syncthreads();
        {
            const bf16_t* Kp = KMb + (size_t)(s0 + srow) * 64 + sseg;
            bf16x8 kv0 = *(const bf16x8*)(Kp);
            bf16x8 kv1 = *(const bf16x8*)(Kp + 8);
            *(bf16x8*)(&Ks[srow * 72 + sseg]) = kv0;
            *(bf16x8*)(&Ks[srow * 72 + sseg + 8]) = kv1;
            const bf16_t* Vp = VMb + (size_t)(s0 + srow) * 64 + sseg;
            bf16x8 vv0 = *(const bf16x8*)(Vp);
            bf16x8 vv1 = *(const bf16x8*)(Vp + 8);
#pragma unroll
            for (int j = 0; j < 8; j++) Vts[(sseg + j) * 72 + srow] = vv0[j];
#pragma unroll
            for (int j = 0; j < 8; j++) Vts[(sseg + 8 + j) * 72 + srow] = vv1[j];
        }
        __syncthreads();

        float sv[4][4];
#pragma unroll
        for (int ni = 0; ni < 4; ni++) {
            floatx4 c = (floatx4){0.f, 0.f, 0.f, 0.f};
            bf16x8 b0 = *(const bf16x8*)(&Ks[(ni * 16 + l16) * 72 + qd * 8]);
            bf16x8 b1 = *(const bf16x8*)(&Ks[(ni * 16 + l16) * 72 + 32 + qd * 8]);
            c = MFMA16(a0, b0, c);
            c = MFMA16(a1, b1, c);
#pragma unroll
            for (int r = 0; r < 4; r++) sv[ni][r] = c[r];
        }

#pragma unroll
        for (int r = 0; r < 4; r++) {
            float mt = fmaxf(fmaxf(sv[0][r], sv[1][r]), fmaxf(sv[2][r], sv[3][r]));
            mt = fmaxf(mt, __shfl_xor(mt, 1));
            mt = fmaxf(mt, __shfl_xor(mt, 2));
            mt = fmaxf(mt, __shfl_xor(mt, 4));
            mt = fmaxf(mt, __shfl_xor(mt, 8));
            const float mnew = fmaxf(mm2[r], mt);
            const float alpha = __expf(mm2[r] - mnew);
            mm2[r] = mnew;
            float ls = 0.f;
#pragma unroll
            for (int ni = 0; ni < 4; ni++) {
                const float p = __expf(sv[ni][r] - mnew);
                sv[ni][r] = p;
                ls += p;
            }
            ls += __shfl_xor(ls, 1);
            ls += __shfl_xor(ls, 2);
            ls += __shfl_xor(ls, 4);
            ls += __shfl_xor(ls, 8);
            lm[r] = lm[r] * alpha + ls;
#pragma unroll
            for (int ni = 0; ni < 4; ni++) Om[ni][r] *= alpha;
#pragma unroll
            for (int ni = 0; ni < 4; ni++)
                Pw[(qd * 4 + r) * 72 + ni * 16 + l16] = (bf16_t)sv[ni][r];
        }
        __syncthreads();
#pragma unroll
        for (int ks = 0; ks < 2; ks++) {
            bf16x8 pf = *(const bf16x8*)(&Pw[l16 * 72 + ks * 32 + qd * 8]);
#pragma unroll
            for (int ni = 0; ni < 4; ni++) {
                bf16x8 vf = *(const bf16x8*)(&Vts[(ni * 16 + l16) * 72 + ks * 32 + qd * 8]);
                Om[ni] = MFMA16(pf, vf, Om[ni]);
            }
        }
    }

    const float gb = f32 ? ((const float*)mbiasv)[h] : (float)((const bf16_t*)mbiasv)[h];
    const float g = 1.f / (1.f + __expf(-gb));
    const int b = bh >> 4;
#pragma unroll
    for (int ni = 0; ni < 4; ni++) {
        const int col = h * 64 + ni * 16 + l16;
#pragma unroll
        for (int r = 0; r < 4; r++) {
            const int tg = trow_base + r;
            const float ol = Ol[ni][r] / ll[r];
            const float om = Om[ni][r] / lm[r];
            const float val = (1.f - g) * ol + g * om;
            att[(size_t)(tg * 2 + b) * 1024 + col] = (bf16_t)val;
        }
    }
}

__global__ void sentinel_kernel(float* o) { o[0] = 30000.0f; }

extern "C" void kernel_launch(void* const* d_in, const int* in_sizes, int n_in,
                              void* d_out, int out_size, void* d_ws, size_t ws_size,
                              hipStream_t stream)
{
    const void* query = d_in[0];
    const void* pos   = d_in[1];
    const void* lcr   = d_in[2];
    const void* q_w   = d_in[3];
    const void* q_b   = d_in[4];
    const void* k_w   = d_in[5];
    const void* k_b   = d_in[6];
    const void* v_w   = d_in[7];
    const void* v_b   = d_in[8];
    const void* out_w = d_in[9];
    const void* out_b = d_in[10];
    const void* mbias = d_in[11];

    const int T = 2048, B = 2, E = 1024, M = 1024;

    const size_t elems = (size_t)(3 * B * 16 * T * 64 + 2 * B * 16 * M * 64 + T * B * E);
    const size_t needed = elems * 2 + 64;
    if (ws_size < needed) {
        sentinel_kernel<<<1, 1, 0, stream>>>((float*)d_out);
        return;
    }

    bf16_t* q_ws  = (bf16_t*)d_ws;
    bf16_t* k_ws  = q_ws + (size_t)B * 16 * T * 64;
    bf16_t* v_ws  = k_ws + (size_t)B * 16 * T * 64;
    bf16_t* km_ws = v_ws + (size_t)B * 16 * T * 64;
    bf16_t* vm_ws = km_ws + (size_t)B * 16 * M * 64;
    bf16_t* att_ws = vm_ws + (size_t)B * 16 * M * 64;
    int* flag = (int*)((char*)d_ws + elems * 2);

    dim3 blk(256);
    dim3 g1(T * B / 128, E / 128);
    dim3 g2(M * B / 128, E / 128);
    dim3 ga(T / 64, B * 16);

    const float scaling = 0.125f;  // D^-0.5, D=64
    const size_t lcr_half = (size_t)M * B * E;  // element offset of lcr[1]

    detect_kernel<<<1, 256, 0, stream>>>((const unsigned short*)query, flag);
    gemm_bt_kernel<<<g1, blk, 0, stream>>>(query, q_w, q_b, q_ws, flag, E, E, scaling, 1, B, T, 1, 0);
    gemm_bt_kernel<<<g1, blk, 0, stream>>>(query, k_w, k_b, k_ws, flag, E, E, 1.0f, 1, B, T, 1, 0);
    gemm_bt_kernel<<<g1, blk, 0, stream>>>(query, v_w, v_b, v_ws, flag, E, E, 1.0f, 1, B, T, 1, 0);
    gemm_bt_kernel<<<g2, blk, 0, stream>>>(lcr, k_w, k_b, km_ws, flag, E, E, 1.0f, 1, B, M, 1, 0);
    gemm_bt_kernel<<<g2, blk, 0, stream>>>(lcr, v_w, v_b, vm_ws, flag, E, E, 1.0f, 1, B, M, 1, lcr_half);
    attn_kernel<<<ga, blk, 0, stream>>>(q_ws, k_ws, v_ws, km_ws, vm_ws, pos, mbias, att_ws, flag, T, M);
    gemm_bt_kernel<<<g1, blk, 0, stream>>>(att_ws, out_w, out_b, d_out, flag, E, E, 1.0f, 0, B, T, 0, 0);
    (void)in_sizes; (void)n_in; (void)out_size;
}

// Round 4
// 888.281 us; speedup vs baseline: 1.1056x; 1.1056x over previous
//
#include <hip/hip_runtime.h>

typedef __bf16 bf16_t;
typedef __bf16 bf16x2 __attribute__((ext_vector_type(2)));
typedef __bf16 bf16x8 __attribute__((ext_vector_type(8)));
typedef float floatx4 __attribute__((ext_vector_type(4)));

#define MFMA16(a, b, c) __builtin_amdgcn_mfma_f32_16x16x32_bf16((a), (b), (c), 0, 0, 0)

__global__ void detect_kernel(const unsigned short* __restrict__ q, int* flag)
{
    __shared__ int cnt;
    if (threadIdx.x == 0) cnt = 0;
    __syncthreads();
    int local = 0;
    for (int i = threadIdx.x; i < 65536; i += 256) {
        unsigned short u = q[i];
        if ((u & 0x7F80u) == 0x7F80u) local++;
    }
    atomicAdd(&cnt, local);
    __syncthreads();
    if (threadIdx.x == 0) flag[0] = (cnt >= 8) ? 1 : 0;
}

__device__ inline void cvt16_f32(const float* __restrict__ p, bf16x8& lo, bf16x8& hi)
{
    float4 a = ((const float4*)p)[0];
    float4 b = ((const float4*)p)[1];
    float4 c = ((const float4*)p)[2];
    float4 d = ((const float4*)p)[3];
    lo[0] = (bf16_t)a.x; lo[1] = (bf16_t)a.y; lo[2] = (bf16_t)a.z; lo[3] = (bf16_t)a.w;
    lo[4] = (bf16_t)b.x; lo[5] = (bf16_t)b.y; lo[6] = (bf16_t)b.z; lo[7] = (bf16_t)b.w;
    hi[0] = (bf16_t)c.x; hi[1] = (bf16_t)c.y; hi[2] = (bf16_t)c.z; hi[3] = (bf16_t)c.w;
    hi[4] = (bf16_t)d.x; hi[5] = (bf16_t)d.y; hi[6] = (bf16_t)d.z; hi[7] = (bf16_t)d.w;
}

// ---------------------------------------------------------------------------
// Merged projection GEMM, flat grid of 1024 blocks, 128x128 tiles, K=1024.
//  blk [0,768):   X=query (4096x1024), virtual W = [q_w;k_w;v_w] (N=3072).
//                 q,k -> mode1 scatter [B,H,2048,64]; v -> mode2 [B,H,64,2048]
//  blk [768,896): X=lcr[0] (2048x1024), W=k_w -> km mode1 [B,H,1024,64]
//  blk [896,1024):X=lcr[1] (2048x1024), W=v_w -> vmT mode2 [B,H,64,1024]
// Row r of X = (t*B+b). X/W/bias external (dtype per flag). Y internal bf16.
// ---------------------------------------------------------------------------
__global__ __launch_bounds__(256) void proj_kernel(
    const void* __restrict__ query, const void* __restrict__ lcr,
    const void* __restrict__ qw, const void* __restrict__ kw,
    const void* __restrict__ vw,
    const void* __restrict__ qbias, const void* __restrict__ kbias,
    const void* __restrict__ vbias,
    bf16_t* __restrict__ q_ws, bf16_t* __restrict__ k_ws,
    bf16_t* __restrict__ vt_ws, bf16_t* __restrict__ km_ws,
    bf16_t* __restrict__ vmt_ws, const int* __restrict__ flag)
{
    __shared__ __attribute__((aligned(16))) bf16_t As[128 * 40];
    __shared__ __attribute__((aligned(16))) bf16_t Bs[128 * 40];

    const int f32 = flag[0];
    const int K = 1024;
    const int blk = blockIdx.x;

    int rm0, wcol, mode, Tdim;
    float scale;
    const void* Xv; size_t xoff0; const void* Wv; const void* biasv; bf16_t* Yv;
    if (blk < 768) {
        rm0 = (blk & 31) * 128;
        const int cn0 = (blk >> 5) * 128;
        const int sel = cn0 >> 10;
        wcol = cn0 & 1023;
        Xv = query; xoff0 = 0; Tdim = 2048;
        if (sel == 0)      { Wv = qw; biasv = qbias; Yv = q_ws;  mode = 1; scale = 0.125f; }
        else if (sel == 1) { Wv = kw; biasv = kbias; Yv = k_ws;  mode = 1; scale = 1.f; }
        else               { Wv = vw; biasv = vbias; Yv = vt_ws; mode = 2; scale = 1.f; }
    } else if (blk < 896) {
        const int b2 = blk - 768;
        rm0 = (b2 & 15) * 128; wcol = (b2 >> 4) * 128;
        Xv = lcr; xoff0 = 0;
        Wv = kw; biasv = kbias; Yv = km_ws; mode = 1; scale = 1.f; Tdim = 1024;
    } else {
        const int b2 = blk - 896;
        rm0 = (b2 & 15) * 128; wcol = (b2 >> 4) * 128;
        Xv = lcr; xoff0 = (size_t)1024 * 2 * 1024;
        Wv = vw; biasv = vbias; Yv = vmt_ws; mode = 2; scale = 1.f; Tdim = 1024;
    }

    const int tid = threadIdx.x;
    const int wvid = tid >> 6, lane = tid & 63;
    const int qd = lane >> 4, l16 = lane & 15;
    const int wm = (wvid >> 1) * 64, wn = (wvid & 1) * 64;

    const int srow = tid >> 1;
    const int sseg = (tid & 1) * 16;
    const size_t xoff = xoff0 + (size_t)(rm0 + srow) * K + sseg;
    const size_t woff = (size_t)(wcol + srow) * K + sseg;
    const bf16_t* Xh = (const bf16_t*)Xv + xoff;
    const float*  Xf = (const float*)Xv + xoff;
    const bf16_t* Wh = (const bf16_t*)Wv + woff;
    const float*  Wf = (const float*)Wv + woff;
    bf16_t* Asw = &As[srow * 40 + sseg];
    bf16_t* Bsw = &Bs[srow * 40 + sseg];

    floatx4 acc[4][4];
#pragma unroll
    for (int i = 0; i < 4; i++)
#pragma unroll
        for (int j = 0; j < 4; j++) acc[i][j] = (floatx4){0.f, 0.f, 0.f, 0.f};

    for (int k0 = 0; k0 < K; k0 += 32) {
        bf16x8 x0, x1, w0, w1;
        if (f32) {
            cvt16_f32(Xf + k0, x0, x1);
            cvt16_f32(Wf + k0, w0, w1);
        } else {
            x0 = *(const bf16x8*)(Xh + k0);
            x1 = *(const bf16x8*)(Xh + k0 + 8);
            w0 = *(const bf16x8*)(Wh + k0);
            w1 = *(const bf16x8*)(Wh + k0 + 8);
        }
        __syncthreads();
        *(bf16x8*)(Asw) = x0;
        *(bf16x8*)(Asw + 8) = x1;
        *(bf16x8*)(Bsw) = w0;
        *(bf16x8*)(Bsw + 8) = w1;
        __syncthreads();

        bf16x8 af[4], bfg[4];
#pragma unroll
        for (int mi = 0; mi < 4; mi++)
            af[mi] = *(const bf16x8*)(&As[(wm + mi * 16 + l16) * 40 + qd * 8]);
#pragma unroll
        for (int ni = 0; ni < 4; ni++)
            bfg[ni] = *(const bf16x8*)(&Bs[(wn + ni * 16 + l16) * 40 + qd * 8]);
#pragma unroll
        for (int mi = 0; mi < 4; mi++)
#pragma unroll
            for (int ni = 0; ni < 4; ni++)
                acc[mi][ni] = MFMA16(af[mi], bfg[ni], acc[mi][ni]);
    }

#pragma unroll
    for (int ni = 0; ni < 4; ni++) {
        const int col = wcol + wn + ni * 16 + l16;
        const float bv = f32 ? ((const float*)biasv)[col]
                             : (float)((const bf16_t*)biasv)[col];
        const int hh = col >> 6, dd = col & 63;
#pragma unroll
        for (int mi = 0; mi < 4; mi++) {
            const int row0 = rm0 + wm + mi * 16 + qd * 4;  // always even
            const int t = row0 >> 1;                       // rows: (t,b=0),(t,1),(t+1,0),(t+1,1)
            const float v0 = (acc[mi][ni][0] + bv) * scale;
            const float v1 = (acc[mi][ni][1] + bv) * scale;
            const float v2 = (acc[mi][ni][2] + bv) * scale;
            const float v3 = (acc[mi][ni][3] + bv) * scale;
            if (mode == 1) {
                Yv[(((size_t)hh * Tdim) + t) * 64 + dd]            = (bf16_t)v0;
                Yv[(((size_t)(16 + hh) * Tdim) + t) * 64 + dd]     = (bf16_t)v1;
                Yv[(((size_t)hh * Tdim) + t + 1) * 64 + dd]        = (bf16_t)v2;
                Yv[(((size_t)(16 + hh) * Tdim) + t + 1) * 64 + dd] = (bf16_t)v3;
            } else {
                bf16x2 p0; p0[0] = (bf16_t)v0; p0[1] = (bf16_t)v2;
                bf16x2 p1; p1[0] = (bf16_t)v1; p1[1] = (bf16_t)v3;
                *(bf16x2*)&Yv[((size_t)hh * 64 + dd) * Tdim + t] = p0;
                *(bf16x2*)&Yv[((size_t)(16 + hh) * 64 + dd) * Tdim + t] = p1;
            }
        }
    }
}

// ---------------------------------------------------------------------------
// Barrier-free flash attention. Block = (qt, y) with y = h*2 + b (pos L2
// reuse across b). 4 waves, each fully independent: wave wv owns q rows
// [qt*64+wv*16, +16). All MFMA A/B fragments loaded directly from global
// (coalesced 16B/lane); V consumed from transposed layout [bh][d][t].
// Only P round-trips through per-wave LDS (stride 88, s_waitcnt, no barrier).
// ---------------------------------------------------------------------------
#define PSTR 88
__global__ __launch_bounds__(256) void attn_kernel(
    const bf16_t* __restrict__ Qg, const bf16_t* __restrict__ Kg,
    const bf16_t* __restrict__ VTg, const bf16_t* __restrict__ KMg,
    const bf16_t* __restrict__ VMTg, const void* __restrict__ posv,
    const void* __restrict__ mbiasv, bf16_t* __restrict__ att,
    const int* __restrict__ flag, int T, int Mlen)
{
    __shared__ __attribute__((aligned(16))) bf16_t Ps[4][16 * PSTR];

    const int f32 = flag[0];
    const int tid = threadIdx.x;
    const int wv = tid >> 6, lane = tid & 63;
    const int qd = lane >> 4, l16 = lane & 15;
    const int qt = blockIdx.x;
    const int y = blockIdx.y;
    const int b = y & 1, h = y >> 1;
    const int bh = b * 16 + h;
    const int t0 = qt * 64;
    const int tw = t0 + wv * 16;

    const bf16_t* Qb  = Qg  + (size_t)bh * T * 64;
    const bf16_t* Kb  = Kg  + (size_t)bh * T * 64;
    const bf16_t* VTb = VTg + (size_t)bh * 64 * T;
    const bf16_t* KMb = KMg + (size_t)bh * Mlen * 64;
    const bf16_t* VMTb = VMTg + (size_t)bh * 64 * Mlen;
    const float*  posf = (const float*)posv + (size_t)h * T * T;
    const bf16_t* posh = (const bf16_t*)posv + (size_t)h * T * T;

    const bf16x8 a0 = *(const bf16x8*)(Qb + (size_t)(tw + l16) * 64 + qd * 8);
    const bf16x8 a1 = *(const bf16x8*)(Qb + (size_t)(tw + l16) * 64 + 32 + qd * 8);

    floatx4 Ol[4], Om[4];
    float ml[4], ll[4], mm2[4], lm[4];
#pragma unroll
    for (int i = 0; i < 4; i++) {
        Ol[i] = (floatx4){0.f, 0.f, 0.f, 0.f};
        Om[i] = (floatx4){0.f, 0.f, 0.f, 0.f};
        ml[i] = -1e9f; ll[i] = 0.f; mm2[i] = -1e9f; lm[i] = 0.f;
    }

    const int trow_base = tw + qd * 4;
    bf16_t* Pw = &Ps[wv][0];

    // ---- pass 1: local causal attention + position encoding ----
    for (int st = 0; st <= qt; ++st) {
        const int s0 = st * 64;
        const bool diag = (st == qt);
        const int nhi = diag ? (wv + 1) : 4;  // skip fully-masked key blocks

        float sv[4][4];
#pragma unroll
        for (int ni = 0; ni < 4; ni++)
#pragma unroll
            for (int r = 0; r < 4; r++) sv[ni][r] = -1e9f;

#pragma unroll
        for (int ni = 0; ni < 4; ni++) {
            if (ni < nhi) {
                const bf16x8 kb0 = *(const bf16x8*)(Kb + (size_t)(s0 + ni * 16 + l16) * 64 + qd * 8);
                const bf16x8 kb1 = *(const bf16x8*)(Kb + (size_t)(s0 + ni * 16 + l16) * 64 + 32 + qd * 8);
                floatx4 c = (floatx4){0.f, 0.f, 0.f, 0.f};
                c = MFMA16(a0, kb0, c);
                c = MFMA16(a1, kb1, c);
                const int sg = s0 + ni * 16 + l16;
#pragma unroll
                for (int r = 0; r < 4; r++) {
                    const int tg = trow_base + r;
                    const size_t pidx = (size_t)tg * T + sg;
                    const float pe = f32 ? posf[pidx] : (float)posh[pidx];
                    float val = c[r] + pe;
                    if (diag && sg > tg) val = -1e9f;
                    sv[ni][r] = val;
                }
            }
        }

#pragma unroll
        for (int r = 0; r < 4; r++) {
            float mt = fmaxf(fmaxf(sv[0][r], sv[1][r]), fmaxf(sv[2][r], sv[3][r]));
            mt = fmaxf(mt, __shfl_xor(mt, 1));
            mt = fmaxf(mt, __shfl_xor(mt, 2));
            mt = fmaxf(mt, __shfl_xor(mt, 4));
            mt = fmaxf(mt, __shfl_xor(mt, 8));
            const float mnew = fmaxf(ml[r], mt);
            const float alpha = __expf(ml[r] - mnew);
            ml[r] = mnew;
            float ls = 0.f;
#pragma unroll
            for (int ni = 0; ni < 4; ni++) {
                const float p = __expf(sv[ni][r] - mnew);
                sv[ni][r] = p;
                ls += p;
            }
            ls += __shfl_xor(ls, 1);
            ls += __shfl_xor(ls, 2);
            ls += __shfl_xor(ls, 4);
            ls += __shfl_xor(ls, 8);
            ll[r] = ll[r] * alpha + ls;
#pragma unroll
            for (int ni = 0; ni < 4; ni++) Ol[ni][r] *= alpha;
#pragma unroll
            for (int ni = 0; ni < 4; ni++)
                Pw[(qd * 4 + r) * PSTR + ni * 16 + l16] = (bf16_t)sv[ni][r];
        }
        asm volatile("s_waitcnt lgkmcnt(0)" ::: "memory");
        const bf16x8 pf0 = *(const bf16x8*)(&Pw[l16 * PSTR + qd * 8]);
        const bf16x8 pf1 = *(const bf16x8*)(&Pw[l16 * PSTR + 32 + qd * 8]);
#pragma unroll
        for (int ni = 0; ni < 4; ni++) {
            const bf16x8 vf0 = *(const bf16x8*)(VTb + (size_t)(ni * 16 + l16) * T + s0 + qd * 8);
            const bf16x8 vf1 = *(const bf16x8*)(VTb + (size_t)(ni * 16 + l16) * T + s0 + 32 + qd * 8);
            Ol[ni] = MFMA16(pf0, vf0, Ol[ni]);
            Ol[ni] = MFMA16(pf1, vf1, Ol[ni]);
        }
    }

    // ---- pass 2: memory attention (no mask, no pos) ----
    for (int st = 0; st < Mlen / 64; ++st) {
        const int s0 = st * 64;
        float sv[4][4];
#pragma unroll
        for (int ni = 0; ni < 4; ni++) {
            const bf16x8 kb0 = *(const bf16x8*)(KMb + (size_t)(s0 + ni * 16 + l16) * 64 + qd * 8);
            const bf16x8 kb1 = *(const bf16x8*)(KMb + (size_t)(s0 + ni * 16 + l16) * 64 + 32 + qd * 8);
            floatx4 c = (floatx4){0.f, 0.f, 0.f, 0.f};
            c = MFMA16(a0, kb0, c);
            c = MFMA16(a1, kb1, c);
#pragma unroll
            for (int r = 0; r < 4; r++) sv[ni][r] = c[r];
        }

#pragma unroll
        for (int r = 0; r < 4; r++) {
            float mt = fmaxf(fmaxf(sv[0][r], sv[1][r]), fmaxf(sv[2][r], sv[3][r]));
            mt = fmaxf(mt, __shfl_xor(mt, 1));
            mt = fmaxf(mt, __shfl_xor(mt, 2));
            mt = fmaxf(mt, __shfl_xor(mt, 4));
            mt = fmaxf(mt, __shfl_xor(mt, 8));
            const float mnew = fmaxf(mm2[r], mt);
            const float alpha = __expf(mm2[r] - mnew);
            mm2[r] = mnew;
            float ls = 0.f;
#pragma unroll
            for (int ni = 0; ni < 4; ni++) {
                const float p = __expf(sv[ni][r] - mnew);
                sv[ni][r] = p;
                ls += p;
            }
            ls += __shfl_xor(ls, 1);
            ls += __shfl_xor(ls, 2);
            ls += __shfl_xor(ls, 4);
            ls += __shfl_xor(ls, 8);
            lm[r] = lm[r] * alpha + ls;
#pragma unroll
            for (int ni = 0; ni < 4; ni++) Om[ni][r] *= alpha;
#pragma unroll
            for (int ni = 0; ni < 4; ni++)
                Pw[(qd * 4 + r) * PSTR + ni * 16 + l16] = (bf16_t)sv[ni][r];
        }
        asm volatile("s_waitcnt lgkmcnt(0)" ::: "memory");
        const bf16x8 pf0 = *(const bf16x8*)(&Pw[l16 * PSTR + qd * 8]);
        const bf16x8 pf1 = *(const bf16x8*)(&Pw[l16 * PSTR + 32 + qd * 8]);
#pragma unroll
        for (int ni = 0; ni < 4; ni++) {
            const bf16x8 vf0 = *(const bf16x8*)(VMTb + (size_t)(ni * 16 + l16) * Mlen + s0 + qd * 8);
            const bf16x8 vf1 = *(const bf16x8*)(VMTb + (size_t)(ni * 16 + l16) * Mlen + s0 + 32 + qd * 8);
            Om[ni] = MFMA16(pf0, vf0, Om[ni]);
            Om[ni] = MFMA16(pf1, vf1, Om[ni]);
        }
    }

    // ---- epilogue: gate-combine, write internal bf16 [T*B, E] ----
    const float gb = f32 ? ((const float*)mbiasv)[h] : (float)((const bf16_t*)mbiasv)[h];
    const float g = 1.f / (1.f + __expf(-gb));
#pragma unroll
    for (int ni = 0; ni < 4; ni++) {
        const int col = h * 64 + ni * 16 + l16;
#pragma unroll
        for (int r = 0; r < 4; r++) {
            const int tg = trow_base + r;
            const float ol = Ol[ni][r] / ll[r];
            const float om = Om[ni][r] / lm[r];
            const float val = (1.f - g) * ol + g * om;
            att[(size_t)(tg * 2 + b) * 1024 + col] = (bf16_t)val;
        }
    }
}

// ---------------------------------------------------------------------------
// Final output projection: Y = att(bf16,[4096x1024]) x out_w^T + out_b.
// 64x128 tile (512 blocks for latency hiding). Wave wv owns cols [wv*32,+32).
// W/bias external dual-dtype; Y external dual-dtype.
// ---------------------------------------------------------------------------
__global__ __launch_bounds__(256) void gemm64_kernel(
    const bf16_t* __restrict__ X, const void* __restrict__ Wv,
    const void* __restrict__ biasv, void* __restrict__ Yv,
    const int* __restrict__ flag)
{
    __shared__ __attribute__((aligned(16))) bf16_t As[64 * 40];
    __shared__ __attribute__((aligned(16))) bf16_t Bs[128 * 40];

    const int f32 = flag[0];
    const int K = 1024, N = 1024;
    const int tid = threadIdx.x;
    const int wvid = tid >> 6, lane = tid & 63;
    const int qd = lane >> 4, l16 = lane & 15;
    const int wn = wvid * 32;
    const int rm0 = blockIdx.x * 64, cn0 = blockIdx.y * 128;

    const int arow = tid >> 1;
    const int aseg = (tid & 1) * 16;
    const bf16_t* Xp = X + (size_t)(rm0 + (arow & 63)) * K + aseg;
    const size_t woff = (size_t)(cn0 + arow) * K + aseg;
    const bf16_t* Wh = (const bf16_t*)Wv + woff;
    const float*  Wf = (const float*)Wv + woff;

    floatx4 acc[4][2];
#pragma unroll
    for (int i = 0; i < 4; i++)
#pragma unroll
        for (int j = 0; j < 2; j++) acc[i][j] = (floatx4){0.f, 0.f, 0.f, 0.f};

    for (int k0 = 0; k0 < K; k0 += 32) {
        bf16x8 x0, x1, w0, w1;
        if (tid < 128) {
            x0 = *(const bf16x8*)(Xp + k0);
            x1 = *(const bf16x8*)(Xp + k0 + 8);
        }
        if (f32) cvt16_f32(Wf + k0, w0, w1);
        else {
            w0 = *(const bf16x8*)(Wh + k0);
            w1 = *(const bf16x8*)(Wh + k0 + 8);
        }
        __syncthreads();
        if (tid < 128) {
            *(bf16x8*)&As[arow * 40 + aseg] = x0;
            *(bf16x8*)&As[arow * 40 + aseg + 8] = x1;
        }
        *(bf16x8*)&Bs[arow * 40 + aseg] = w0;
        *(bf16x8*)&Bs[arow * 40 + aseg + 8] = w1;
        __syncthreads();

        bf16x8 af[4], bfg[2];
#pragma unroll
        for (int mi = 0; mi < 4; mi++)
            af[mi] = *(const bf16x8*)(&As[(mi * 16 + l16) * 40 + qd * 8]);
#pragma unroll
        for (int ni = 0; ni < 2; ni++)
            bfg[ni] = *(const bf16x8*)(&Bs[(wn + ni * 16 + l16) * 40 + qd * 8]);
#pragma unroll
        for (int mi = 0; mi < 4; mi++)
#pragma unroll
            for (int ni = 0; ni < 2; ni++)
                acc[mi][ni] = MFMA16(af[mi], bfg[ni], acc[mi][ni]);
    }

#pragma unroll
    for (int ni = 0; ni < 2; ni++) {
        const int col = cn0 + wn + ni * 16 + l16;
        const float bv = f32 ? ((const float*)biasv)[col]
                             : (float)((const bf16_t*)biasv)[col];
#pragma unroll
        for (int mi = 0; mi < 4; mi++) {
            const int row0 = rm0 + mi * 16 + qd * 4;
#pragma unroll
            for (int r = 0; r < 4; r++) {
                const int row = row0 + r;
                const float val = acc[mi][ni][r] + bv;
                if (f32) ((float*)Yv)[(size_t)row * N + col] = val;
                else ((bf16_t*)Yv)[(size_t)row * N + col] = (bf16_t)val;
            }
        }
    }
}

__global__ void sentinel_kernel(float* o) { o[0] = 30000.0f; }

extern "C" void kernel_launch(void* const* d_in, const int* in_sizes, int n_in,
                              void* d_out, int out_size, void* d_ws, size_t ws_size,
                              hipStream_t stream)
{
    const void* query = d_in[0];
    const void* pos   = d_in[1];
    const void* lcr   = d_in[2];
    const void* q_w   = d_in[3];
    const void* q_b   = d_in[4];
    const void* k_w   = d_in[5];
    const void* k_b   = d_in[6];
    const void* v_w   = d_in[7];
    const void* v_b   = d_in[8];
    const void* out_w = d_in[9];
    const void* out_b = d_in[10];
    const void* mbias = d_in[11];

    const int T = 2048, B = 2, E = 1024, M = 1024;

    const size_t elems = (size_t)(3 * B * 16 * T * 64 + 2 * B * 16 * M * 64 + T * B * E);
    const size_t needed = elems * 2 + 64;
    if (ws_size < needed) {
        sentinel_kernel<<<1, 1, 0, stream>>>((float*)d_out);
        return;
    }

    bf16_t* q_ws   = (bf16_t*)d_ws;
    bf16_t* k_ws   = q_ws + (size_t)B * 16 * T * 64;
    bf16_t* vt_ws  = k_ws + (size_t)B * 16 * T * 64;   // [B,H,64,T]
    bf16_t* km_ws  = vt_ws + (size_t)B * 16 * T * 64;
    bf16_t* vmt_ws = km_ws + (size_t)B * 16 * M * 64;  // [B,H,64,M]
    bf16_t* att_ws = vmt_ws + (size_t)B * 16 * M * 64;
    int* flag = (int*)((char*)d_ws + elems * 2);

    detect_kernel<<<1, 256, 0, stream>>>((const unsigned short*)query, flag);
    proj_kernel<<<1024, 256, 0, stream>>>(query, lcr, q_w, k_w, v_w,
                                          q_b, k_b, v_b,
                                          q_ws, k_ws, vt_ws, km_ws, vmt_ws, flag);
    attn_kernel<<<dim3(T / 64, 32), 256, 0, stream>>>(
        q_ws, k_ws, vt_ws, km_ws, vmt_ws, pos, mbias, att_ws, flag, T, M);
    gemm64_kernel<<<dim3(T * B / 64, E / 128), 256, 0, stream>>>(
        att_ws, out_w, out_b, d_out, flag);
    (void)in_sizes; (void)n_in; (void)out_size;
}